// Round 1
// baseline (177.660 us; speedup 1.0000x reference)
//
#include <hip/hip_runtime.h>
#include <math.h>

#define N_VAR 8192
#define N_CHK 4096
#define DC 6
#define N_EDGE 24576          // N_VAR*3 == N_CHK*6
#define BATCH 512
#define N_ITER 5
#define CLIP_F 0.99999988f    // float32(1 - 1e-7), matches jnp/np clip in fp32

// ---- workspace layout: [0, N_CHK) int counters | [N_CHK, N_CHK + N_CHK*DC) chk_edges ----

__global__ void k_zero(int* __restrict__ cnt) {
    int i = blockIdx.x * blockDim.x + threadIdx.x;
    if (i < N_CHK) cnt[i] = 0;
}

__global__ void k_build(const int* __restrict__ chk_index,
                        int* __restrict__ cnt,
                        int* __restrict__ chk_edges) {
    int e = blockIdx.x * blockDim.x + threadIdx.x;
    if (e < N_EDGE) {
        int c = chk_index[e];
        int p = atomicAdd(&cnt[c], 1);
        chk_edges[c * DC + p] = e;
    }
}

// tanh(msg/2) = sign(msg) * (1 - e^{-|msg|}) / (1 + e^{-|msg|})
__device__ __forceinline__ float tanh_half(float msg) {
    float u = __expf(-fabsf(msg));
    float t = (1.0f - u) * __builtin_amdgcn_rcpf(1.0f + u);
    return msg < 0.0f ? -t : t;
}

__launch_bounds__(1024)
__global__ void k_spa(const float* __restrict__ llr,
                      const int* __restrict__ chk_edges,
                      float* __restrict__ out) {
    // Entire edge state for one batch element lives in LDS across all iterations.
    __shared__ float m[N_EDGE];   // 96 KB: holds ext (var phase in) / tanh-msgs (check phase in), in place
    const int b = blockIdx.x;
    const int tid = threadIdx.x;
    const float* __restrict__ lrow = llr + (size_t)b * N_VAR;
    float* __restrict__ orow = out + (size_t)b * N_VAR;

    #pragma unroll 1
    for (int iter = 0; iter < N_ITER; ++iter) {
        // ---- variable-node phase: edges of var v are 3v,3v+1,3v+2 (var_index = repeat) ----
        for (int v = tid; v < N_VAR; v += 1024) {
            float l = lrow[v];
            float e0 = 0.0f, e1 = 0.0f, e2 = 0.0f, vs = 0.0f;
            if (iter > 0) {
                e0 = m[3 * v]; e1 = m[3 * v + 1]; e2 = m[3 * v + 2];
                vs = e0 + e1 + e2;
                // output of previous iteration: segment_sum(ext) + llr
                orow[(size_t)(iter - 1) * (BATCH * N_VAR) + v] = vs + l;
            }
            // msg = (vsum - ext) + llr ; store tanh(msg/2) in place (disjoint per var)
            m[3 * v]     = tanh_half((vs - e0) + l);
            m[3 * v + 1] = tanh_half((vs - e1) + l);
            m[3 * v + 2] = tanh_half((vs - e2) + l);
        }
        __syncthreads();

        // ---- check-node phase: leave-one-out product over the 6 edges of each check ----
        for (int c = tid; c < N_CHK; c += 1024) {
            int   e[DC];
            float t[DC];
            #pragma unroll
            for (int j = 0; j < DC; ++j) e[j] = chk_edges[c * DC + j];
            #pragma unroll
            for (int j = 0; j < DC; ++j) t[j] = m[e[j]];

            float pre[DC + 1], suf[DC + 1];
            pre[0] = 1.0f; suf[DC] = 1.0f;
            #pragma unroll
            for (int j = 0; j < DC; ++j)      pre[j + 1] = pre[j] * t[j];
            #pragma unroll
            for (int j = DC - 1; j >= 0; --j) suf[j] = suf[j + 1] * t[j];

            // reference: cprod_sgn==0 (some tanh exactly 0) zeroes the whole check
            bool zz = (pre[DC] == 0.0f);

            #pragma unroll
            for (int j = 0; j < DC; ++j) {
                float lo = pre[j] * suf[j + 1];                    // signed leave-one-out product
                lo = fminf(fmaxf(lo, -CLIP_F), CLIP_F);
                // 2*atanh(lo) = log((1+lo)/(1-lo))
                float ex = __logf(__fdividef(1.0f + lo, 1.0f - lo));
                m[e[j]] = zz ? 0.0f : ex;                          // new ext, in place (disjoint per check)
            }
        }
        __syncthreads();
    }

    // ---- final iteration's output ----
    for (int v = tid; v < N_VAR; v += 1024) {
        float vs = m[3 * v] + m[3 * v + 1] + m[3 * v + 2];
        orow[(size_t)(N_ITER - 1) * (BATCH * N_VAR) + v] = vs + lrow[v];
    }
}

extern "C" void kernel_launch(void* const* d_in, const int* in_sizes, int n_in,
                              void* d_out, int out_size, void* d_ws, size_t ws_size,
                              hipStream_t stream) {
    const float* llr       = (const float*)d_in[0];
    // d_in[1] = var_index: deterministic repeat(arange(N_VAR),3) — structure used directly
    const int*   chk_index = (const int*)d_in[2];
    float*       out       = (float*)d_out;

    int* cnt       = (int*)d_ws;
    int* chk_edges = cnt + N_CHK;

    k_zero <<<(N_CHK  + 255) / 256, 256, 0, stream>>>(cnt);
    k_build<<<(N_EDGE + 255) / 256, 256, 0, stream>>>(chk_index, cnt, chk_edges);
    k_spa  <<<BATCH, 1024, 0, stream>>>(llr, chk_edges, out);
}

// Round 2
// 145.217 us; speedup vs baseline: 1.2234x; 1.2234x over previous
//
#include <hip/hip_runtime.h>
#include <math.h>

#define N_VAR 8192
#define N_CHK 4096
#define DC 6
#define DV 3
#define N_EDGE 24576          // N_VAR*3 == N_CHK*6
#define BATCH 512
#define N_ITER 5
#define CLIP_F 0.99999988f    // float32(1 - 1e-7), matches jnp/np clip in fp32
#define NTHREADS 1024
#define VPT (N_VAR / NTHREADS)   // 8 vars per thread
#define CPT (N_CHK / NTHREADS)   // 4 checks per thread

// ---- workspace layout: [0, N_CHK) int counters | [N_CHK, N_CHK + N_CHK*DC) chk_edges ----

__global__ void k_zero(int* __restrict__ cnt) {
    int i = blockIdx.x * blockDim.x + threadIdx.x;
    if (i < N_CHK) cnt[i] = 0;
}

__global__ void k_build(const int* __restrict__ chk_index,
                        int* __restrict__ cnt,
                        int* __restrict__ chk_edges) {
    int e = blockIdx.x * blockDim.x + threadIdx.x;
    if (e < N_EDGE) {
        int c = chk_index[e];
        int p = atomicAdd(&cnt[c], 1);
        // slot order within a check is irrelevant (LOO product is symmetric)
        chk_edges[c * DC + p] = e;
    }
}

// q-domain SPA: LDS m[] holds t = tanh(msg/2) after the var phase and
// q = exp(ext) after the check phase. exp(msg) = exp(llr) * prod(q_other),
// so the var phase needs NO transcendentals; the check phase needs none
// either (q_new = (1+lo)/(1-lo)). Only the per-iteration marginal output
// pays one log per var: out = llr + log(q0*q1*q2).
__launch_bounds__(1024)
__global__ void k_spa(const float* __restrict__ llr,
                      const int* __restrict__ chk_edges,
                      float* __restrict__ out) {
    __shared__ float m[N_EDGE];   // 96 KB, 1 block/CU
    const int b = blockIdx.x;
    const int tid = threadIdx.x;
    const float* __restrict__ lrow = llr + (size_t)b * N_VAR;
    float* __restrict__ orow = out + (size_t)b * N_VAR;

    // iteration-invariant per-thread state in registers
    float l[VPT], el[VPT];
    #pragma unroll
    for (int k = 0; k < VPT; ++k) {
        int v = tid + k * NTHREADS;
        l[k]  = lrow[v];
        el[k] = __expf(l[k]);     // exp(llr): the only exp, once per var total
    }
    int ce[CPT][DC];
    #pragma unroll
    for (int k = 0; k < CPT; ++k) {
        int c = tid + k * NTHREADS;
        #pragma unroll
        for (int j = 0; j < DC; ++j) ce[k][j] = chk_edges[c * DC + j];
    }

    #pragma unroll 1
    for (int iter = 0; iter < N_ITER; ++iter) {
        // ---- variable-node phase (edges of var v are 3v..3v+2) ----
        #pragma unroll
        for (int k = 0; k < VPT; ++k) {
            int v = tid + k * NTHREADS;
            float E0, E1, E2;
            if (iter == 0) {
                E0 = E1 = E2 = el[k];          // ext=0 -> q=1
            } else {
                float q0 = m[3 * v], q1 = m[3 * v + 1], q2 = m[3 * v + 2];
                float q01 = q0 * q1, q12 = q1 * q2, q02 = q0 * q2;
                // previous iteration's marginal: llr + sum(ext) = llr + log(q0q1q2)
                orow[(size_t)(iter - 1) * (BATCH * N_VAR) + v] = l[k] + __logf(q01 * q2);
                E0 = el[k] * q12; E1 = el[k] * q02; E2 = el[k] * q01;
            }
            // t = tanh(msg/2) = (E-1)/(E+1), E = exp(msg) > 0
            m[3 * v]     = (E0 - 1.0f) * __builtin_amdgcn_rcpf(E0 + 1.0f);
            m[3 * v + 1] = (E1 - 1.0f) * __builtin_amdgcn_rcpf(E1 + 1.0f);
            m[3 * v + 2] = (E2 - 1.0f) * __builtin_amdgcn_rcpf(E2 + 1.0f);
        }
        __syncthreads();

        // ---- check-node phase: leave-one-out product over 6 edges ----
        #pragma unroll
        for (int k = 0; k < CPT; ++k) {
            float t[DC];
            #pragma unroll
            for (int j = 0; j < DC; ++j) t[j] = m[ce[k][j]];
            float pre[DC + 1], suf[DC + 1];
            pre[0] = 1.0f; suf[DC] = 1.0f;
            #pragma unroll
            for (int j = 0; j < DC; ++j)      pre[j + 1] = pre[j] * t[j];
            #pragma unroll
            for (int j = DC - 1; j >= 0; --j) suf[j] = suf[j + 1] * t[j];
            bool zz = (pre[DC] == 0.0f);      // some t==0 zeroes the whole check (sign prod = 0)
            #pragma unroll
            for (int j = 0; j < DC; ++j) {
                float lo = pre[j] * suf[j + 1];
                lo = fminf(fmaxf(lo, -CLIP_F), CLIP_F);
                // q = exp(2*atanh(lo)) = (1+lo)/(1-lo); ext=0 -> q=1
                float q = (1.0f + lo) * __builtin_amdgcn_rcpf(1.0f - lo);
                m[ce[k][j]] = zz ? 1.0f : q;
            }
        }
        __syncthreads();
    }

    // ---- final iteration's output ----
    #pragma unroll
    for (int k = 0; k < VPT; ++k) {
        int v = tid + k * NTHREADS;
        float q3 = m[3 * v] * m[3 * v + 1] * m[3 * v + 2];
        orow[(size_t)(N_ITER - 1) * (BATCH * N_VAR) + v] = l[k] + __logf(q3);
    }
}

extern "C" void kernel_launch(void* const* d_in, const int* in_sizes, int n_in,
                              void* d_out, int out_size, void* d_ws, size_t ws_size,
                              hipStream_t stream) {
    const float* llr       = (const float*)d_in[0];
    // d_in[1] = var_index: deterministic repeat(arange(N_VAR),3) — structure used directly
    const int*   chk_index = (const int*)d_in[2];
    float*       out       = (float*)d_out;

    int* cnt       = (int*)d_ws;
    int* chk_edges = cnt + N_CHK;

    k_zero <<<(N_CHK  + 255) / 256, 256, 0, stream>>>(cnt);
    k_build<<<(N_EDGE + 255) / 256, 256, 0, stream>>>(chk_index, cnt, chk_edges);
    k_spa  <<<BATCH, 1024, 0, stream>>>(llr, chk_edges, out);
}

// Round 3
// 143.627 us; speedup vs baseline: 1.2370x; 1.0111x over previous
//
#include <hip/hip_runtime.h>
#include <math.h>

#define N_VAR 8192
#define N_CHK 4096
#define DC 6
#define N_EDGE 24576          // N_VAR*3 == N_CHK*6
#define BATCH 512
#define N_ITER 5
#define CLIP_F 0.99999988f    // float32(1 - 1e-7), matches jnp/np clip in fp32
#define NTHREADS 1024
#define VPT (N_VAR / NTHREADS)   // 8 vars per thread
#define CPT (N_CHK / NTHREADS)   // 4 checks per thread

// ---- workspace layout: [0, N_CHK) int counters | [N_CHK, N_CHK + N_CHK*DC) chk_edges ----

__global__ void k_zero(int* __restrict__ cnt) {
    int i = blockIdx.x * blockDim.x + threadIdx.x;
    if (i < N_CHK) cnt[i] = 0;
}

__global__ void k_build(const int* __restrict__ chk_index,
                        int* __restrict__ cnt,
                        int* __restrict__ chk_edges) {
    int e = blockIdx.x * blockDim.x + threadIdx.x;
    if (e < N_EDGE) {
        int c = chk_index[e];
        int p = atomicAdd(&cnt[c], 1);
        // slot order within a check is irrelevant (LOO product is symmetric)
        chk_edges[c * DC + p] = e;
    }
}

// q-domain SPA (see R2): LDS m[] alternates t = tanh(msg/2) / q = exp(ext).
// This version restructures each phase into load-all -> compute-all -> store-all
// so all scattered LDS reads are in flight under one lgkmcnt wait (latency was
// the bottleneck: per-SIMD VALU issue ~14%, 4 waves/SIMD, 52 VGPRs of ILP).
__launch_bounds__(1024, 4)   // cap VGPR at 128: keep all 16 waves resident
__global__ void k_spa(const float* __restrict__ llr,
                      const int* __restrict__ chk_edges,
                      float* __restrict__ out) {
    __shared__ float m[N_EDGE];   // 96 KB, 1 block/CU
    const int b = blockIdx.x;
    const int tid = threadIdx.x;
    const float* __restrict__ lrow = llr + (size_t)b * N_VAR;
    float* __restrict__ orow = out + (size_t)b * N_VAR;

    // iteration-invariant per-thread state in registers
    float l[VPT], el[VPT];
    #pragma unroll
    for (int k = 0; k < VPT; ++k) {
        int v = tid + k * NTHREADS;
        l[k]  = lrow[v];
        el[k] = __expf(l[k]);     // exp(llr): once per var total
    }
    int ce[CPT][DC];
    #pragma unroll
    for (int k = 0; k < CPT; ++k) {
        int c = tid + k * NTHREADS;
        #pragma unroll
        for (int j = 0; j < DC; ++j) ce[k][j] = chk_edges[c * DC + j];
    }

    // ---- iter-0 variable phase: ext=0 -> msg=llr -> t=(el-1)/(el+1), same on all 3 edges ----
    #pragma unroll
    for (int k = 0; k < VPT; ++k) {
        int v = tid + k * NTHREADS;
        float t0 = (el[k] - 1.0f) * __builtin_amdgcn_rcpf(el[k] + 1.0f);
        m[3 * v] = t0; m[3 * v + 1] = t0; m[3 * v + 2] = t0;
    }
    __syncthreads();

    #pragma unroll 1
    for (int iter = 0; iter < N_ITER; ++iter) {
        // ---- check phase: gather all 24 t's, compute, scatter all 24 q's ----
        float tq[CPT][DC];
        #pragma unroll
        for (int k = 0; k < CPT; ++k)
            #pragma unroll
            for (int j = 0; j < DC; ++j) tq[k][j] = m[ce[k][j]];

        #pragma unroll
        for (int k = 0; k < CPT; ++k) {
            float pre[DC + 1], suf[DC + 1];
            pre[0] = 1.0f; suf[DC] = 1.0f;
            #pragma unroll
            for (int j = 0; j < DC; ++j)      pre[j + 1] = pre[j] * tq[k][j];
            #pragma unroll
            for (int j = DC - 1; j >= 0; --j) suf[j] = suf[j + 1] * tq[k][j];
            bool zz = (pre[DC] == 0.0f);      // some t==0 zeroes the whole check (sign prod = 0)
            #pragma unroll
            for (int j = 0; j < DC; ++j) {
                float lo = pre[j] * suf[j + 1];
                lo = fminf(fmaxf(lo, -CLIP_F), CLIP_F);
                float q = (1.0f + lo) * __builtin_amdgcn_rcpf(1.0f - lo);
                tq[k][j] = zz ? 1.0f : q;     // overwrite in place: saves 24 VGPRs
            }
        }

        #pragma unroll
        for (int k = 0; k < CPT; ++k)
            #pragma unroll
            for (int j = 0; j < DC; ++j) m[ce[k][j]] = tq[k][j];
        __syncthreads();

        // ---- variable phase: load all 24 q's (contiguous, conflict-free), then compute ----
        float qv[VPT][3];
        #pragma unroll
        for (int k = 0; k < VPT; ++k) {
            int v = tid + k * NTHREADS;
            qv[k][0] = m[3 * v]; qv[k][1] = m[3 * v + 1]; qv[k][2] = m[3 * v + 2];
        }

        const bool last = (iter == N_ITER - 1);
        #pragma unroll
        for (int k = 0; k < VPT; ++k) {
            int v = tid + k * NTHREADS;
            float q0 = qv[k][0], q1 = qv[k][1], q2 = qv[k][2];
            float q01 = q0 * q1, q12 = q1 * q2, q02 = q0 * q2;
            // this iteration's marginal: llr + sum(ext) = llr + log(q0q1q2)
            orow[(size_t)iter * (BATCH * N_VAR) + v] = l[k] + __logf(q01 * q2);
            if (!last) {
                float E0 = el[k] * q12, E1 = el[k] * q02, E2 = el[k] * q01;
                m[3 * v]     = (E0 - 1.0f) * __builtin_amdgcn_rcpf(E0 + 1.0f);
                m[3 * v + 1] = (E1 - 1.0f) * __builtin_amdgcn_rcpf(E1 + 1.0f);
                m[3 * v + 2] = (E2 - 1.0f) * __builtin_amdgcn_rcpf(E2 + 1.0f);
            }
        }
        if (!last) __syncthreads();
    }
}

extern "C" void kernel_launch(void* const* d_in, const int* in_sizes, int n_in,
                              void* d_out, int out_size, void* d_ws, size_t ws_size,
                              hipStream_t stream) {
    const float* llr       = (const float*)d_in[0];
    // d_in[1] = var_index: deterministic repeat(arange(N_VAR),3) — structure used directly
    const int*   chk_index = (const int*)d_in[2];
    float*       out       = (float*)d_out;

    int* cnt       = (int*)d_ws;
    int* chk_edges = cnt + N_CHK;

    k_zero <<<(N_CHK  + 255) / 256, 256, 0, stream>>>(cnt);
    k_build<<<(N_EDGE + 255) / 256, 256, 0, stream>>>(chk_index, cnt, chk_edges);
    k_spa  <<<BATCH, 1024, 0, stream>>>(llr, chk_edges, out);
}